// Round 11
// baseline (390.427 us; speedup 1.0000x reference)
//
#include <hip/hip_runtime.h>

typedef float f4 __attribute__((ext_vector_type(4)));

constexpr int NN = 100000;
constexpr int NE = 1600000;
constexpr int SCAN_BLK = 1024;
constexpr int NB = (NN + SCAN_BLK - 1) / SCAN_BLK;    // 98 scan blocks

__device__ __forceinline__ f4 relu_add(f4 a, f4 b) {
    f4 s = a + b;
    s.x = fmaxf(s.x, 0.f);
    s.y = fmaxf(s.y, 0.f);
    s.z = fmaxf(s.z, 0.f);
    s.w = fmaxf(s.w, 0.f);
    return s;
}

__device__ __forceinline__ f4 bf16x4_to_f4(uint2 u) {
    f4 r;
    r.x = __uint_as_float((u.x & 0xFFFFu) << 16);
    r.y = __uint_as_float(u.x & 0xFFFF0000u);
    r.z = __uint_as_float((u.y & 0xFFFFu) << 16);
    r.w = __uint_as_float(u.y & 0xFFFF0000u);
    return r;
}

__device__ __forceinline__ unsigned short f2bf(float f) {
    unsigned u = __float_as_uint(f);
    u = (u + 0x7FFFu + ((u >> 16) & 1u)) >> 16;   // round-to-nearest-even
    return (unsigned short)u;
}

// ---------------- fallback path (used only if ws too small) -------------------

__global__ __launch_bounds__(256) void k_init(const float* __restrict__ x,
                                              const float* __restrict__ eps,
                                              float* __restrict__ out) {
    const float s = 1.0f + eps[0];
    const float4* x4 = (const float4*)x;
    float4* o4 = (float4*)out;
    const int total = NN * 16;
    for (int i = blockIdx.x * blockDim.x + threadIdx.x; i < total;
         i += gridDim.x * blockDim.x) {
        float4 v = x4[i];
        v.x *= s; v.y *= s; v.z *= s; v.w *= s;
        o4[i] = v;
    }
}

__global__ __launch_bounds__(256) void k_edges(const float* __restrict__ x,
                                               const int* __restrict__ ei,
                                               const float* __restrict__ ea,
                                               float* __restrict__ out) {
    const int* dst = ei;
    const int* src = ei + NE;
    const float4* ea4 = (const float4*)ea;
    const float4* x4 = (const float4*)x;
    const int total = NE * 16;
    for (int g = blockIdx.x * blockDim.x + threadIdx.x; g < total;
         g += gridDim.x * blockDim.x) {
        const int e = g >> 4;
        const int c = g & 15;
        const int s = src[e];
        const int d = dst[e];
        float4 a  = ea4[g];
        float4 xv = x4[s * 16 + c];
        float* base = out + d * 64 + c * 4;
        atomicAdd(base + 0, fmaxf(xv.x + a.x, 0.0f));
        atomicAdd(base + 1, fmaxf(xv.y + a.y, 0.0f));
        atomicAdd(base + 2, fmaxf(xv.z + a.z, 0.0f));
        atomicAdd(base + 3, fmaxf(xv.w + a.w, 0.0f));
    }
}

__global__ __launch_bounds__(256) void k_linear2(const float* __restrict__ W,
                                                 const float* __restrict__ bias,
                                                 float* __restrict__ out) {
    __shared__ float Ws[64 * 64];
    __shared__ float bs[64];
    for (int i = threadIdx.x; i < 1024; i += 256)
        ((float4*)Ws)[i] = ((const float4*)W)[i];
    if (threadIdx.x < 16)
        ((float4*)bs)[threadIdx.x] = ((const float4*)bias)[threadIdx.x];
    __syncthreads();

    const int l16 = threadIdx.x & 15;
    const int gid = (blockIdx.x * 256 + threadIdx.x) >> 4;
    const float4* Ws4 = (const float4*)Ws;
    float4* out4 = (float4*)out;

    const float4 h4 = out4[gid * 16 + l16];
    float4 o = ((const float4*)bs)[l16];
#pragma unroll
    for (int d = 0; d < 64; ++d) {
        const int q = d >> 2;
        const int r = d & 3;
        float hd;
        if (r == 0)      hd = __shfl(h4.x, q, 16);
        else if (r == 1) hd = __shfl(h4.y, q, 16);
        else if (r == 2) hd = __shfl(h4.z, q, 16);
        else             hd = __shfl(h4.w, q, 16);
        const float4 w = Ws4[d * 16 + l16];
        o.x = fmaf(hd, w.x, o.x);
        o.y = fmaf(hd, w.y, o.y);
        o.z = fmaf(hd, w.z, o.z);
        o.w = fmaf(hd, w.w, o.w);
    }
    out4[gid * 16 + l16] = o;
}

// ---------------- main path ----------------------------------------------------

// fused: x (fp32) -> xb (bf16) table  +  dst histogram
__global__ __launch_bounds__(256) void k_cvt_hist(const float* __restrict__ x,
                                                  const int* __restrict__ dst,
                                                  unsigned short* __restrict__ xb,
                                                  int* __restrict__ counts) {
    const int tid = blockIdx.x * blockDim.x + threadIdx.x;
    const int nthr = gridDim.x * blockDim.x;

    const float4* x4 = (const float4*)x;
    const int xtotal = NN * 16;
    for (int i = tid; i < xtotal; i += nthr) {
        const float4 v = x4[i];
        ushort4 o;
        o.x = f2bf(v.x); o.y = f2bf(v.y); o.z = f2bf(v.z); o.w = f2bf(v.w);
        ((ushort4*)xb)[i] = o;
    }

    const int4* d4 = (const int4*)dst;
    const int htotal = NE / 4;
    for (int i = tid; i < htotal; i += nthr) {
        const int4 d = d4[i];
        atomicAdd(&counts[d.x], 1);
        atomicAdd(&counts[d.y], 1);
        atomicAdd(&counts[d.z], 1);
        atomicAdd(&counts[d.w], 1);
    }
}

__global__ __launch_bounds__(256) void k_scan_block(const int* __restrict__ counts,
                                                    int* __restrict__ offsets,
                                                    int* __restrict__ bsum) {
    __shared__ int sd[256];
    const int t = threadIdx.x;
    const int base = blockIdx.x * SCAN_BLK;
    int c[4];
    int s = 0;
#pragma unroll
    for (int k = 0; k < 4; ++k) {
        const int i = base + t * 4 + k;
        c[k] = (i < NN) ? counts[i] : 0;
        s += c[k];
    }
    sd[t] = s;
    __syncthreads();
#pragma unroll
    for (int off = 1; off < 256; off <<= 1) {
        int v = (t >= off) ? sd[t - off] : 0;
        __syncthreads();
        sd[t] += v;
        __syncthreads();
    }
    int excl = sd[t] - s;
#pragma unroll
    for (int k = 0; k < 4; ++k) {
        const int i = base + t * 4 + k;
        if (i < NN) offsets[i] = excl;
        excl += c[k];
    }
    if (t == 255) bsum[blockIdx.x] = sd[255];
}

// fused scan of the 98 block sums (redundant per block) + global fixup
__global__ __launch_bounds__(256) void k_scan_finish(int* __restrict__ offsets,
                                                     const int* __restrict__ bsum,
                                                     int* __restrict__ cursor) {
    __shared__ int sd[128];
    const int t = threadIdx.x;
    if (t < 128) {
        const int v = (t < NB) ? bsum[t] : 0;
        sd[t] = v;
    }
    __syncthreads();
#pragma unroll
    for (int off = 1; off < 128; off <<= 1) {
        int u = 0;
        if (t < 128 && t >= off) u = sd[t - off];
        __syncthreads();
        if (t < 128) sd[t] += u;
        __syncthreads();
    }
    // sd now inclusive; exclusive base for block b is sd[b] - bsum[b]
    for (int i = blockIdx.x * blockDim.x + t; i < NN;
         i += gridDim.x * blockDim.x) {
        const int b = i >> 10;
        const int v = offsets[i] + sd[b] - bsum[b];
        offsets[i] = v;
        cursor[i] = v;
    }
    if (blockIdx.x == 0 && t == 0) offsets[NN] = NE;
}

// fused: scatter {edge, src} into dst-sorted order  +  ea (fp32) -> eab (bf16).
// The bf16 edge table (205 MB) FITS IN THE 256MB INFINITY CACHE -> the agg's
// permuted row reads become L3 hits instead of HBM misses.
__global__ __launch_bounds__(256) void k_scatter_cvt(const int* __restrict__ dst,
                                                     const int* __restrict__ src,
                                                     int* __restrict__ cursor,
                                                     int2* __restrict__ ps,
                                                     const float* __restrict__ ea,
                                                     unsigned short* __restrict__ eab) {
    const int tid = blockIdx.x * blockDim.x + threadIdx.x;
    const int nthr = gridDim.x * blockDim.x;

    const int4* d4 = (const int4*)dst;
    const int4* s4 = (const int4*)src;
    const int stotal = NE / 4;
    for (int i = tid; i < stotal; i += nthr) {
        const int4 d = d4[i];
        const int4 s = s4[i];
        const int e = i * 4;
        int p0 = atomicAdd(&cursor[d.x], 1);
        int p1 = atomicAdd(&cursor[d.y], 1);
        int p2 = atomicAdd(&cursor[d.z], 1);
        int p3 = atomicAdd(&cursor[d.w], 1);
        ps[p0] = make_int2(e + 0, s.x);
        ps[p1] = make_int2(e + 1, s.y);
        ps[p2] = make_int2(e + 2, s.z);
        ps[p3] = make_int2(e + 3, s.w);
    }

    const float4* ea4 = (const float4*)ea;
    const int ctotal = NE * 16;   // float4 count
    for (int i = tid; i < ctotal; i += nthr) {
        const float4 v = ea4[i];
        ushort4 o;
        o.x = f2bf(v.x); o.y = f2bf(v.y); o.z = f2bf(v.z); o.w = f2bf(v.w);
        ((ushort4*)eab)[i] = o;
    }
}

// Fused per-node aggregation + self-term + linear.
// One node per 16-lane group, 6250 blocks exactly. Branchless unroll-4 edge
// loop; BOTH gathers are bf16 (x table 12.8MB L2-ish, ea table 205MB L3-fit);
// self-term from exact fp32 x; epilogue h @ W + b with W in LDS.
__global__ __launch_bounds__(256, 4) void k_agg_lin(const float* __restrict__ x,
                                                    const unsigned short* __restrict__ xb,
                                                    const unsigned short* __restrict__ eab,
                                                    const int* __restrict__ offsets,
                                                    const int2* __restrict__ ps,
                                                    const float* __restrict__ epsp,
                                                    const float* __restrict__ W,
                                                    const float* __restrict__ bias,
                                                    float* __restrict__ out) {
    __shared__ float Ws[64 * 64];
    __shared__ float bs[64];
    for (int i = threadIdx.x; i < 1024; i += 256)
        ((float4*)Ws)[i] = ((const float4*)W)[i];
    if (threadIdx.x < 16)
        ((float4*)bs)[threadIdx.x] = ((const float4*)bias)[threadIdx.x];
    __syncthreads();

    const int l16 = threadIdx.x & 15;
    const int n = (blockIdx.x * 256 + threadIdx.x) >> 4;   // node id, < NN exact
    const float epsv = 1.0f + epsp[0];
    const f4* x4 = (const f4*)x;
    const f4* Ws4 = (const f4*)Ws;
    f4* out4 = (f4*)out;

    const int beg = offsets[n];
    const int end = offsets[n + 1];
    f4 acc = {0.f, 0.f, 0.f, 0.f};

    int j = beg;
    for (; j + 4 <= end; j += 4) {
        const int2 d0 = ps[j];
        const int2 d1 = ps[j + 1];
        const int2 d2 = ps[j + 2];
        const int2 d3 = ps[j + 3];
        const uint2 au0 = *(const uint2*)&eab[(size_t)d0.x * 64 + l16 * 4];
        const uint2 xu0 = *(const uint2*)&xb[(size_t)d0.y * 64 + l16 * 4];
        const uint2 au1 = *(const uint2*)&eab[(size_t)d1.x * 64 + l16 * 4];
        const uint2 xu1 = *(const uint2*)&xb[(size_t)d1.y * 64 + l16 * 4];
        const uint2 au2 = *(const uint2*)&eab[(size_t)d2.x * 64 + l16 * 4];
        const uint2 xu2 = *(const uint2*)&xb[(size_t)d2.y * 64 + l16 * 4];
        const uint2 au3 = *(const uint2*)&eab[(size_t)d3.x * 64 + l16 * 4];
        const uint2 xu3 = *(const uint2*)&xb[(size_t)d3.y * 64 + l16 * 4];
        acc += relu_add(bf16x4_to_f4(xu0), bf16x4_to_f4(au0));
        acc += relu_add(bf16x4_to_f4(xu1), bf16x4_to_f4(au1));
        acc += relu_add(bf16x4_to_f4(xu2), bf16x4_to_f4(au2));
        acc += relu_add(bf16x4_to_f4(xu3), bf16x4_to_f4(au3));
    }
    for (; j < end; ++j) {                   // tail (0..3 edges; also deg<4)
        const int2 d = ps[j];
        const uint2 au = *(const uint2*)&eab[(size_t)d.x * 64 + l16 * 4];
        const uint2 xu = *(const uint2*)&xb[(size_t)d.y * 64 + l16 * 4];
        acc += relu_add(bf16x4_to_f4(xu), bf16x4_to_f4(au));
    }

    // self term from exact fp32 x
    const f4 xs = x4[n * 16 + l16];
    f4 h;
    h.x = fmaf(xs.x, epsv, acc.x);
    h.y = fmaf(xs.y, epsv, acc.y);
    h.z = fmaf(xs.z, epsv, acc.z);
    h.w = fmaf(xs.w, epsv, acc.w);

    // fused linear: o[l16*4+k] = b + sum_d h[d] * W[d][l16*4+k]
    f4 o = ((const f4*)bs)[l16];
#pragma unroll
    for (int d = 0; d < 64; ++d) {
        const int q = d >> 2;
        const int r = d & 3;
        float hd;
        if (r == 0)      hd = __shfl(h.x, q, 16);
        else if (r == 1) hd = __shfl(h.y, q, 16);
        else if (r == 2) hd = __shfl(h.z, q, 16);
        else             hd = __shfl(h.w, q, 16);
        const f4 w = Ws4[d * 16 + l16];
        o.x = fmaf(hd, w.x, o.x);
        o.y = fmaf(hd, w.y, o.y);
        o.z = fmaf(hd, w.z, o.z);
        o.w = fmaf(hd, w.w, o.w);
    }
    out4[n * 16 + l16] = o;
}

extern "C" void kernel_launch(void* const* d_in, const int* in_sizes, int n_in,
                              void* d_out, int out_size, void* d_ws, size_t ws_size,
                              hipStream_t stream) {
    const float* x   = (const float*)d_in[0];
    const int*   ei  = (const int*)d_in[1];
    const float* ea  = (const float*)d_in[2];
    const float* eps = (const float*)d_in[3];
    const float* W   = (const float*)d_in[4];
    const float* b   = (const float*)d_in[5];
    float* out = (float*)d_out;

    const int* dst = ei;        // edge_index[0]
    const int* src = ei + NE;   // edge_index[1]

    // workspace layout: ps, xb, eab, ints
    int2* ps     = (int2*)d_ws;                        // NE          (12.8 MB)
    unsigned short* xb  = (unsigned short*)(ps + NE);  // NN*64 bf16  (12.8 MB)
    unsigned short* eab = xb + (size_t)NN * 64;        // NE*64 bf16  (204.8 MB)
    int* counts  = (int*)(eab + (size_t)NE * 64);      // NN
    int* offsets = counts + NN;                        // NN + 1
    int* cursor  = offsets + NN + 1;                   // NN
    int* bsum    = cursor + NN;                        // 128
    const size_t ws_needed = (size_t)NE * 8 + (size_t)NN * 128 +
                             (size_t)NE * 128 +
                             (size_t)(3 * NN + 1 + 128) * sizeof(int);

    if (ws_size < ws_needed) {            // insurance: atomic fallback
        k_init<<<2048, 256, 0, stream>>>(x, eps, out);
        k_edges<<<2048, 256, 0, stream>>>(x, ei, ea, out);
        k_linear2<<<NN * 16 / 256, 256, 0, stream>>>(W, b, out);
        return;
    }

    hipMemsetAsync(counts, 0, (size_t)NN * sizeof(int), stream);
    k_cvt_hist<<<1024, 256, 0, stream>>>(x, dst, xb, counts);
    k_scan_block<<<NB, 256, 0, stream>>>(counts, offsets, bsum);
    k_scan_finish<<<256, 256, 0, stream>>>(offsets, bsum, cursor);
    k_scatter_cvt<<<2048, 256, 0, stream>>>(dst, src, cursor, ps, ea, eab);
    k_agg_lin<<<NN * 16 / 256, 256, 0, stream>>>(x, xb, eab, offsets, ps, eps,
                                                 W, b, out);
}